// Round 8
// baseline (1727.606 us; speedup 1.0000x reference)
//
#include <hip/hip_runtime.h>

#define NPTS 2048
#define NB   16
#define WGS  512     // threads per wg (8 waves)
#define ARRV 32      // wgs per batch = barrier arrivals

// eps = 0.01, log-domain Sinkhorn in base-2.
constexpr float K_R          = 144.26950408889634f;     // log2(e)/eps
constexpr float K_TWO_R      = 288.53900817779268f;     // 2R
constexpr float K_INV2R      = 0.0034657359027997264f;  // 1/(2R)
constexpr float K_EPS_LN2    = 0.0069314718055994531f;  // 1/R = eps*ln2
constexpr float K_EPS_LOGMRG = -0.076246189861593985f;  // eps*ln(1/2048)

__device__ __forceinline__ float fexp2(float x) { return __builtin_amdgcn_exp2f(x); }
__device__ __forceinline__ float flog2(float x) { return __builtin_amdgcn_logf(x); }

// ---------------------------------------------------------------- prep ------
// Packed panels: (p*2R, -|p|^2*R). Raw p recoverable via *K_INV2R.
__global__ __launch_bounds__(256) void prep_kernel(
    const float* __restrict__ x, const float* __restrict__ y,
    float4* __restrict__ px, float4* __restrict__ py, float* __restrict__ g)
{
    int idx = blockIdx.x * 256 + threadIdx.x;
    if (idx >= NB * NPTS) return;
    float x0 = x[idx*3+0], x1 = x[idx*3+1], x2 = x[idx*3+2];
    float xx = fmaf(x0,x0, fmaf(x1,x1, x2*x2));
    px[idx] = make_float4(x0*K_TWO_R, x1*K_TWO_R, x2*K_TWO_R, -xx*K_R);
    float y0 = y[idx*3+0], y1 = y[idx*3+1], y2 = y[idx*3+2];
    float yy = fmaf(y0,y0, fmaf(y1,y1, y2*y2));
    py[idx] = make_float4(y0*K_TWO_R, y1*K_TWO_R, y2*K_TWO_R, -yy*K_R);
    g[idx] = 0.0f;
}

// --------------------------------------------------------- batch barrier ----
// Monotonic 32-arrival per-batch barrier. Fences hoisted OUT of the spin:
// RELEASE (buffer_wbl2: push dirty dual lines to MALL) once before arrive,
// ACQUIRE (buffer_inv) once after observe. Spin = RELAXED loads, no inv.
__device__ __forceinline__ void batch_barrier(unsigned* ctr, unsigned target) {
    __syncthreads();
    if (threadIdx.x == 0) {
        __builtin_amdgcn_fence(__ATOMIC_RELEASE, "agent");
        __hip_atomic_fetch_add(ctr, 1u, __ATOMIC_RELAXED, __HIP_MEMORY_SCOPE_AGENT);
        while (__hip_atomic_load(ctr, __ATOMIC_RELAXED, __HIP_MEMORY_SCOPE_AGENT)
               < target)
            __builtin_amdgcn_s_sleep(2);
        __builtin_amdgcn_fence(__ATOMIC_ACQUIRE, "agent");
    }
    __syncthreads();
}

// ------------------------------------------------------- persistent core ----
// Grid 512 = 2 wgs/CU x 256 CU, guaranteed co-resident (LDS 72KB<80, VGPR<=128).
// Both packed panels pinned in LDS all 100 phases; only duals cross phases.
__global__ __launch_bounds__(512, 4) void sinkhorn_fused(
    const float4* __restrict__ px4, const float4* __restrict__ py4,
    float* __restrict__ f, float* __restrict__ g,
    unsigned* __restrict__ bar, float* __restrict__ out)
{
    __shared__ float4 ldY[NPTS];   // 32 KB  (y*2R, -|y|^2 R)
    __shared__ float4 ldX[NPTS];   // 32 KB  (x*2R, -|x|^2 R)
    __shared__ float  hd [NPTS];   //  8 KB  current duals * R
    __shared__ float  wsum[8];

    const int bid   = blockIdx.x;
    const int b     = bid >> 5;
    const int chunk = bid & 31;
    const int tid   = threadIdx.x;
    const int lane  = tid & 63;
    const int wid   = tid >> 6;          // 0..7
    const int row0  = chunk * 64 + wid * 8;

    const float4* pyb = py4 + b * NPTS;
    const float4* pxb = px4 + b * NPTS;
    float* fb = f + b * NPTS;
    float* gb = g + b * NPTS;
    unsigned* ctr = bar + b * 64;        // 256 B apart

    #pragma unroll
    for (int i2 = 0; i2 < 4; ++i2) {
        int k = i2 * WGS + tid;
        ldY[k] = pyb[k];
        ldX[k] = pxb[k];
    }

    float rxf[8], ryf[8], rzf[8], u0f[8];   // x rows (f-update, emd)
    float rxg[8], ryg[8], rzg[8], u0g[8];   // y rows (g-update)
    #pragma unroll
    for (int r = 0; r < 8; ++r) {
        float4 p = pxb[row0 + r];
        rxf[r] = p.x * K_INV2R; ryf[r] = p.y * K_INV2R; rzf[r] = p.z * K_INV2R;
        u0f[r] = p.w;
        float4 q2 = pyb[row0 + r];
        rxg[r] = q2.x * K_INV2R; ryg[r] = q2.y * K_INV2R; rzg[r] = q2.z * K_INV2R;
        u0g[r] = q2.w;
    }

    auto half_phase = [&](const float4* ldP, float (&rx)[8], float (&ry)[8],
                          float (&rz)[8], float (&u0)[8], float* dual_out_row) {
        float acc[8] = {0.f,0.f,0.f,0.f,0.f,0.f,0.f,0.f};
        #pragma unroll 4
        for (int c = 0; c < 32; ++c) {
            float4 p = ldP[c * 64 + lane];
            float  h = hd [c * 64 + lane];
            float tmp = p.w + h;
            #pragma unroll
            for (int r = 0; r < 8; ++r) {
                float w = fmaf(p.x, rx[r], fmaf(p.y, ry[r], fmaf(p.z, rz[r], tmp + u0[r])));
                acc[r] += fexp2(w);
            }
        }
        #pragma unroll
        for (int r = 0; r < 8; ++r) {
            #pragma unroll
            for (int off = 1; off < 64; off <<= 1)
                acc[r] += __shfl_xor(acc[r], off, 64);
        }
        if (lane < 8) {
            float s = acc[0];
            #pragma unroll
            for (int r = 1; r < 8; ++r) s = (lane == r) ? acc[r] : s;
            dual_out_row[lane] = K_EPS_LOGMRG - K_EPS_LN2 * flog2(s);
        }
    };

    unsigned tgt = ARRV;
    for (int it = 0; it < 50; ++it) {
        // ---- f-update: duals g ----
        #pragma unroll
        for (int i2 = 0; i2 < 4; ++i2) {
            int k = i2 * WGS + tid;
            hd[k] = gb[k] * K_R;
        }
        __syncthreads();
        half_phase(ldY, rxf, ryf, rzf, u0f, &fb[row0]);
        batch_barrier(ctr, tgt); tgt += ARRV;

        // ---- g-update: duals f ----
        #pragma unroll
        for (int i2 = 0; i2 < 4; ++i2) {
            int k = i2 * WGS + tid;
            hd[k] = fb[k] * K_R;
        }
        __syncthreads();
        half_phase(ldX, rxg, ryg, rzg, u0g, &gb[row0]);
        batch_barrier(ctr, tgt); tgt += ARRV;
    }

    // ---- EMD:  w = (g_j - C_ij)R;  P = 2^(w + f_i R);  C*R = hd_j - w ----
    #pragma unroll
    for (int i2 = 0; i2 < 4; ++i2) {
        int k = i2 * WGS + tid;
        hd[k] = gb[k] * K_R;
    }
    float fR[8];
    #pragma unroll
    for (int r = 0; r < 8; ++r) fR[r] = fb[row0 + r] * K_R;
    __syncthreads();

    float acc = 0.f;
    #pragma unroll 4
    for (int c = 0; c < 32; ++c) {
        float4 p = ldY[c * 64 + lane];
        float  h = hd [c * 64 + lane];
        float tmp = p.w + h;
        #pragma unroll
        for (int r = 0; r < 8; ++r) {
            float w = fmaf(p.x, rxf[r], fmaf(p.y, ryf[r], fmaf(p.z, rzf[r], tmp + u0f[r])));
            acc = fmaf(fexp2(w + fR[r]), h - w, acc);
        }
    }
    #pragma unroll
    for (int off = 1; off < 64; off <<= 1) acc += __shfl_xor(acc, off, 64);
    if (lane == 0) wsum[wid] = acc;
    __syncthreads();
    if (tid == 0) {
        float s = 0.f;
        #pragma unroll
        for (int i2 = 0; i2 < 8; ++i2) s += wsum[i2];
        atomicAdd(&out[b], s * K_EPS_LN2);
    }
}

// -------------------------------------------------------------- launch ------
extern "C" void kernel_launch(void* const* d_in, const int* in_sizes, int n_in,
                              void* d_out, int out_size, void* d_ws, size_t ws_size,
                              hipStream_t stream)
{
    const float* x = (const float*)d_in[0];
    const float* y = (const float*)d_in[1];
    float* out = (float*)d_out;

    char* ws = (char*)d_ws;
    float4*   px  = (float4*)(ws);
    float4*   py  = (float4*)(ws + (size_t)NB * NPTS * 16);
    float*    f   = (float*)  (ws + (size_t)NB * NPTS * 32);
    float*    g   = (float*)  (ws + (size_t)NB * NPTS * 32 + (size_t)NB * NPTS * 4);
    unsigned* bar = (unsigned*)(ws + (size_t)NB * NPTS * 32 + (size_t)NB * NPTS * 8);

    hipMemsetAsync(d_out, 0, (size_t)out_size * sizeof(float), stream);
    hipMemsetAsync(bar, 0, NB * 64 * sizeof(unsigned), stream);

    prep_kernel<<<(NB * NPTS + 255) / 256, 256, 0, stream>>>(x, y, px, py, g);
    sinkhorn_fused<<<NB * ARRV, WGS, 0, stream>>>(px, py, f, g, bar, out);
}

// Round 9
// 1492.134 us; speedup vs baseline: 1.1578x; 1.1578x over previous
//
#include <hip/hip_runtime.h>

#define NPTS 2048
#define NB   16
#define WGS  512     // threads per wg (8 waves)
#define ARRV 32      // wgs per batch = barrier arrivals

// eps = 0.01, log-domain Sinkhorn in base-2. Duals stored PRE-SCALED by
// R = 1/(eps*ln2)  (i.e. in log2-units). -log2(2048) = -11 exactly.
constexpr float K_R          = 144.26950408889634f;     // log2(e)/eps
constexpr float K_TWO_R      = 288.53900817779268f;     // 2R
constexpr float K_INV2R      = 0.0034657359027997264f;  // 1/(2R)
constexpr float K_EPS_LN2    = 0.0069314718055994531f;  // 1/R = eps*ln2

__device__ __forceinline__ float fexp2(float x) { return __builtin_amdgcn_exp2f(x); }
__device__ __forceinline__ float flog2(float x) { return __builtin_amdgcn_logf(x); }

// duals via agent-scope RELAXED (MALL-serialized; no cache invalidates)
__device__ __forceinline__ float aload(const float* p) {
    return __hip_atomic_load(p, __ATOMIC_RELAXED, __HIP_MEMORY_SCOPE_AGENT);
}
__device__ __forceinline__ void astore(float* p, float v) {
    __hip_atomic_store(p, v, __ATOMIC_RELAXED, __HIP_MEMORY_SCOPE_AGENT);
}

// ---------------------------------------------------------------- prep ------
// Packed panels: (p*2R, -|p|^2*R). Raw p recoverable via *K_INV2R.
__global__ __launch_bounds__(256) void prep_kernel(
    const float* __restrict__ x, const float* __restrict__ y,
    float4* __restrict__ px, float4* __restrict__ py, float* __restrict__ g)
{
    int idx = blockIdx.x * 256 + threadIdx.x;
    if (idx >= NB * NPTS) return;
    float x0 = x[idx*3+0], x1 = x[idx*3+1], x2 = x[idx*3+2];
    float xx = fmaf(x0,x0, fmaf(x1,x1, x2*x2));
    px[idx] = make_float4(x0*K_TWO_R, x1*K_TWO_R, x2*K_TWO_R, -xx*K_R);
    float y0 = y[idx*3+0], y1 = y[idx*3+1], y2 = y[idx*3+2];
    float yy = fmaf(y0,y0, fmaf(y1,y1, y2*y2));
    py[idx] = make_float4(y0*K_TWO_R, y1*K_TWO_R, y2*K_TWO_R, -yy*K_R);
    g[idx] = 0.0f;   // g*R = 0
}

// --------------------------------------------------------- batch barrier ----
// Monotonic 32-arrival per-batch barrier, FENCE-FREE (R5 protocol):
// dual astores (sc1 -> MALL) drained by vmcnt(0), then RELAXED fetch_add at
// MALL serializes after them; waiters' subsequent aloads hit MALL -> fresh.
// No buffer_inv / no wbL2 -> L2-resident data stays resident.
__device__ __forceinline__ void batch_barrier(unsigned* ctr, unsigned target) {
    __syncthreads();
    if (threadIdx.x == 0) {
        asm volatile("s_waitcnt vmcnt(0)" ::: "memory");
        __hip_atomic_fetch_add(ctr, 1u, __ATOMIC_RELAXED, __HIP_MEMORY_SCOPE_AGENT);
        while (__hip_atomic_load(ctr, __ATOMIC_RELAXED, __HIP_MEMORY_SCOPE_AGENT)
               < target)
            __builtin_amdgcn_s_sleep(1);
        asm volatile("" ::: "memory");
    }
    __syncthreads();
}

// ------------------------------------------------------- persistent core ----
// Grid 512 = 2 wgs/CU x 256 CU co-resident (LDS 72KB, VGPR<=128).
// Both packed panels pinned in LDS all 100 phases; only duals cross phases.
__global__ __launch_bounds__(512, 4) void sinkhorn_fused(
    const float4* __restrict__ px4, const float4* __restrict__ py4,
    float* __restrict__ f, float* __restrict__ g,
    unsigned* __restrict__ bar, float* __restrict__ out)
{
    __shared__ float4 ldY[NPTS];   // 32 KB  (y*2R, -|y|^2 R)
    __shared__ float4 ldX[NPTS];   // 32 KB  (x*2R, -|x|^2 R)
    __shared__ float  hd [NPTS];   //  8 KB  current duals (R-units)
    __shared__ float  wsum[8];

    const int bid   = blockIdx.x;
    const int b     = bid >> 5;
    const int chunk = bid & 31;
    const int tid   = threadIdx.x;
    const int lane  = tid & 63;
    const int wid   = tid >> 6;          // 0..7
    const int row0  = chunk * 64 + wid * 8;

    const float4* pyb = py4 + b * NPTS;
    const float4* pxb = px4 + b * NPTS;
    float* fb = f + b * NPTS;
    float* gb = g + b * NPTS;
    unsigned* ctr = bar + b * 64;        // 256 B apart

    #pragma unroll
    for (int i2 = 0; i2 < 4; ++i2) {
        int k = i2 * WGS + tid;
        ldY[k] = pyb[k];
        ldX[k] = pxb[k];
    }

    float rxf[8], ryf[8], rzf[8], u0f[8];   // x rows (f-update, emd)
    float rxg[8], ryg[8], rzg[8], u0g[8];   // y rows (g-update)
    #pragma unroll
    for (int r = 0; r < 8; ++r) {
        float4 p = pxb[row0 + r];
        rxf[r] = p.x * K_INV2R; ryf[r] = p.y * K_INV2R; rzf[r] = p.z * K_INV2R;
        u0f[r] = p.w;
        float4 q2 = pyb[row0 + r];
        rxg[r] = q2.x * K_INV2R; ryg[r] = q2.y * K_INV2R; rzg[r] = q2.z * K_INV2R;
        u0g[r] = q2.w;
    }

    auto half_phase = [&](const float4* ldP, float (&rx)[8], float (&ry)[8],
                          float (&rz)[8], float (&u0)[8], float* dual_out_row) {
        float acc[8] = {0.f,0.f,0.f,0.f,0.f,0.f,0.f,0.f};
        #pragma unroll 4
        for (int c = 0; c < 32; ++c) {
            float4 p = ldP[c * 64 + lane];
            float  h = hd [c * 64 + lane];
            float tmp = p.w + h;
            #pragma unroll
            for (int r = 0; r < 8; ++r) {
                float w = fmaf(p.x, rx[r], fmaf(p.y, ry[r], fmaf(p.z, rz[r], tmp + u0[r])));
                acc[r] += fexp2(w);
            }
        }
        #pragma unroll
        for (int r = 0; r < 8; ++r) {
            #pragma unroll
            for (int off = 1; off < 64; off <<= 1)
                acc[r] += __shfl_xor(acc[r], off, 64);
        }
        if (lane < 8) {
            float s = acc[0];
            #pragma unroll
            for (int r = 1; r < 8; ++r) s = (lane == r) ? acc[r] : s;
            astore(&dual_out_row[lane], -11.0f - flog2(s));   // R-units
        }
    };

    unsigned tgt = ARRV;
    for (int it = 0; it < 50; ++it) {
        // ---- f-update: duals g ----
        #pragma unroll
        for (int i2 = 0; i2 < 4; ++i2) {
            int k = i2 * WGS + tid;
            hd[k] = aload(&gb[k]);
        }
        __syncthreads();
        half_phase(ldY, rxf, ryf, rzf, u0f, &fb[row0]);
        batch_barrier(ctr, tgt); tgt += ARRV;

        // ---- g-update: duals f ----
        #pragma unroll
        for (int i2 = 0; i2 < 4; ++i2) {
            int k = i2 * WGS + tid;
            hd[k] = aload(&fb[k]);
        }
        __syncthreads();
        half_phase(ldX, rxg, ryg, rzg, u0g, &gb[row0]);
        batch_barrier(ctr, tgt); tgt += ARRV;
    }

    // ---- EMD:  w = (g_j - C_ij)R;  P = 2^(w + fR_i);  C*R = hd_j - w ----
    #pragma unroll
    for (int i2 = 0; i2 < 4; ++i2) {
        int k = i2 * WGS + tid;
        hd[k] = aload(&gb[k]);
    }
    float fR[8];
    #pragma unroll
    for (int r = 0; r < 8; ++r) fR[r] = aload(&fb[row0 + r]);
    __syncthreads();

    float acc = 0.f;
    #pragma unroll 4
    for (int c = 0; c < 32; ++c) {
        float4 p = ldY[c * 64 + lane];
        float  h = hd [c * 64 + lane];
        float tmp = p.w + h;
        #pragma unroll
        for (int r = 0; r < 8; ++r) {
            float w = fmaf(p.x, rxf[r], fmaf(p.y, ryf[r], fmaf(p.z, rzf[r], tmp + u0f[r])));
            acc = fmaf(fexp2(w + fR[r]), h - w, acc);
        }
    }
    #pragma unroll
    for (int off = 1; off < 64; off <<= 1) acc += __shfl_xor(acc, off, 64);
    if (lane == 0) wsum[wid] = acc;
    __syncthreads();
    if (tid == 0) {
        float s = 0.f;
        #pragma unroll
        for (int i2 = 0; i2 < 8; ++i2) s += wsum[i2];
        atomicAdd(&out[b], s * K_EPS_LN2);
    }
}

// -------------------------------------------------------------- launch ------
extern "C" void kernel_launch(void* const* d_in, const int* in_sizes, int n_in,
                              void* d_out, int out_size, void* d_ws, size_t ws_size,
                              hipStream_t stream)
{
    const float* x = (const float*)d_in[0];
    const float* y = (const float*)d_in[1];
    float* out = (float*)d_out;

    char* ws = (char*)d_ws;
    float4*   px  = (float4*)(ws);
    float4*   py  = (float4*)(ws + (size_t)NB * NPTS * 16);
    float*    f   = (float*)  (ws + (size_t)NB * NPTS * 32);
    float*    g   = (float*)  (ws + (size_t)NB * NPTS * 32 + (size_t)NB * NPTS * 4);
    unsigned* bar = (unsigned*)(ws + (size_t)NB * NPTS * 32 + (size_t)NB * NPTS * 8);

    hipMemsetAsync(d_out, 0, (size_t)out_size * sizeof(float), stream);
    hipMemsetAsync(bar, 0, NB * 64 * sizeof(unsigned), stream);

    prep_kernel<<<(NB * NPTS + 255) / 256, 256, 0, stream>>>(x, y, px, py, g);
    sinkhorn_fused<<<NB * ARRV, WGS, 0, stream>>>(px, py, f, g, bar, out);
}

// Round 10
// 1274.099 us; speedup vs baseline: 1.3559x; 1.1711x over previous
//
#include <hip/hip_runtime.h>

#define NPTS 2048
#define NB   16
#define WGS  512     // threads per wg (8 waves)
#define ARRV 32      // wgs per batch = barrier arrivals

typedef float v2f __attribute__((ext_vector_type(2)));

// eps = 0.01, log-domain Sinkhorn in base-2. Duals stored PRE-SCALED by
// R = 1/(eps*ln2) (log2-units). -log2(2048) = -11 exactly.
constexpr float K_R       = 144.26950408889634f;     // log2(e)/eps
constexpr float K_TWO_R   = 288.53900817779268f;     // 2R
constexpr float K_INV2R   = 0.0034657359027997264f;  // 1/(2R)
constexpr float K_EPS_LN2 = 0.0069314718055994531f;  // 1/R

__device__ __forceinline__ float fexp2(float x) { return __builtin_amdgcn_exp2f(x); }
__device__ __forceinline__ float flog2(float x) { return __builtin_amdgcn_logf(x); }

__device__ __forceinline__ float aload(const float* p) {
    return __hip_atomic_load(p, __ATOMIC_RELAXED, __HIP_MEMORY_SCOPE_AGENT);
}
__device__ __forceinline__ void astore(float* p, float v) {
    __hip_atomic_store(p, v, __ATOMIC_RELAXED, __HIP_MEMORY_SCOPE_AGENT);
}

// ---------------------------------------------------------------- prep ------
// Packed: (p*2R, -|p|^2*R)
__global__ __launch_bounds__(256) void prep_kernel(
    const float* __restrict__ x, const float* __restrict__ y,
    float4* __restrict__ px, float4* __restrict__ py, float* __restrict__ g)
{
    int idx = blockIdx.x * 256 + threadIdx.x;
    if (idx >= NB * NPTS) return;
    float x0 = x[idx*3+0], x1 = x[idx*3+1], x2 = x[idx*3+2];
    float xx = fmaf(x0,x0, fmaf(x1,x1, x2*x2));
    px[idx] = make_float4(x0*K_TWO_R, x1*K_TWO_R, x2*K_TWO_R, -xx*K_R);
    float y0 = y[idx*3+0], y1 = y[idx*3+1], y2 = y[idx*3+2];
    float yy = fmaf(y0,y0, fmaf(y1,y1, y2*y2));
    py[idx] = make_float4(y0*K_TWO_R, y1*K_TWO_R, y2*K_TWO_R, -yy*K_R);
    g[idx] = 0.0f;   // g*R = 0
}

// --------------------------------------------------------- batch barrier ----
// Fence-free monotonic barrier (R9 protocol, verified absmax 0.0).
__device__ __forceinline__ void batch_barrier(unsigned* ctr, unsigned target) {
    __syncthreads();
    if (threadIdx.x == 0) {
        asm volatile("s_waitcnt vmcnt(0)" ::: "memory");
        __hip_atomic_fetch_add(ctr, 1u, __ATOMIC_RELAXED, __HIP_MEMORY_SCOPE_AGENT);
        while (__hip_atomic_load(ctr, __ATOMIC_RELAXED, __HIP_MEMORY_SCOPE_AGENT)
               < target)
            __builtin_amdgcn_s_sleep(1);
        asm volatile("" ::: "memory");
    }
    __syncthreads();
}

// ------------------------------------------------------- persistent core ----
// 512 wgs = 2/CU x 256 CU co-resident. SoA j-pair planes in LDS (~78 KB/wg):
// packed-f32 (v_pk_*) inner loop, 2 visits per pk-chain.
__global__ __launch_bounds__(512, 4) void sinkhorn_fused(
    const float4* __restrict__ px4, const float4* __restrict__ py4,
    float* __restrict__ f, float* __restrict__ g,
    unsigned* __restrict__ bar, float* __restrict__ out)
{
    __shared__ v2f vyx[1024], vyy[1024], vyz[1024], vyw[1024];  // Y*2R, -|y|^2 R
    __shared__ v2f vxx[1024], vxy[1024], vxz[1024], vxw[1024];  // X*2R, -|x|^2 R
    __shared__ v2f vhw[1024];          // per-phase: wplane + dual (R-units)
    __shared__ v2f rowp[512];          // pre-broadcast row constants, both phases
    __shared__ float wsum[8];

    const int bid   = blockIdx.x;
    const int b     = bid >> 5;
    const int chunk = bid & 31;
    const int tid   = threadIdx.x;
    const int lane  = tid & 63;
    const int wid   = tid >> 6;           // 0..7
    const int row0  = chunk * 64 + wid * 8;

    const float4* pyb = py4 + b * NPTS;
    const float4* pxb = px4 + b * NPTS;
    float* fb = f + b * NPTS;
    float* gb = g + b * NPTS;
    unsigned* ctr = bar + b * 64;

    // ---- stage SoA planes ----
    #pragma unroll
    for (int i2 = 0; i2 < 4; ++i2) {
        int k = i2 * WGS + tid;
        float4 p = pyb[k];
        ((float*)vyx)[k] = p.x; ((float*)vyy)[k] = p.y;
        ((float*)vyz)[k] = p.z; ((float*)vyw)[k] = p.w;
        float4 q2 = pxb[k];
        ((float*)vxx)[k] = q2.x; ((float*)vxy)[k] = q2.y;
        ((float*)vxz)[k] = q2.z; ((float*)vxw)[k] = q2.w;
    }
    // ---- row constants, pre-broadcast into pairs (1 per thread) ----
    {
        int ph = tid >> 8;                 // 0: f-rows (x), 1: g-rows (y)
        int w8 = (tid >> 5) & 7;
        int r  = (tid >> 2) & 7;
        int cp = tid & 3;
        float4 p = (ph ? pyb : pxb)[chunk * 64 + w8 * 8 + r];
        float v = (cp == 0) ? p.x * K_INV2R :
                  (cp == 1) ? p.y * K_INV2R :
                  (cp == 2) ? p.z * K_INV2R : p.w;
        v2f t; t.x = v; t.y = v;
        rowp[(ph * 8 + w8) * 32 + r * 4 + cp] = t;
    }

    auto run_phase = [&](const v2f* PX, const v2f* PY, const v2f* PZ,
                         int ph, float* dual_out) {
        v2f rx2[8], ry2[8], rz2[8], u02[8];
        const v2f* rp = &rowp[(ph * 8 + wid) * 32];
        #pragma unroll
        for (int r = 0; r < 8; ++r) {
            rx2[r] = rp[r*4+0]; ry2[r] = rp[r*4+1];
            rz2[r] = rp[r*4+2]; u02[r] = rp[r*4+3];
        }
        v2f acc2[8];
        #pragma unroll
        for (int r = 0; r < 8; ++r) { acc2[r].x = 0.f; acc2[r].y = 0.f; }

        #pragma unroll 2
        for (int c = 0; c < 16; ++c) {
            int jp = c * 64 + lane;
            v2f X = PX[jp], Y = PY[jp], Z = PZ[jp], H = vhw[jp];
            #pragma unroll
            for (int r = 0; r < 8; ++r) {
                v2f w = Z * rz2[r] + (H + u02[r]);
                w = Y * ry2[r] + w;
                w = X * rx2[r] + w;
                v2f e; e.x = fexp2(w.x); e.y = fexp2(w.y);
                acc2[r] += e;
            }
        }

        float sv[8];
        #pragma unroll
        for (int r = 0; r < 8; ++r) {
            float s = acc2[r].x + acc2[r].y;
            #pragma unroll
            for (int off = 1; off < 64; off <<= 1)
                s += __shfl_xor(s, off, 64);
            sv[r] = s;
        }
        if (lane < 8) {
            float s = sv[0];
            #pragma unroll
            for (int r = 1; r < 8; ++r) s = (lane == r) ? sv[r] : s;
            astore(&dual_out[lane], -11.0f - flog2(s));
        }
    };

    unsigned tgt = ARRV;
    for (int it = 0; it < 50; ++it) {
        // ---- f-update: hw = yw + gR ----
        #pragma unroll
        for (int i2 = 0; i2 < 4; ++i2) {
            int k = i2 * WGS + tid;
            ((float*)vhw)[k] = ((const float*)vyw)[k] + aload(&gb[k]);
        }
        __syncthreads();
        run_phase(vyx, vyy, vyz, 0, &fb[row0]);
        batch_barrier(ctr, tgt); tgt += ARRV;

        // ---- g-update: hw = xw + fR ----
        #pragma unroll
        for (int i2 = 0; i2 < 4; ++i2) {
            int k = i2 * WGS + tid;
            ((float*)vhw)[k] = ((const float*)vxw)[k] + aload(&fb[k]);
        }
        __syncthreads();
        run_phase(vxx, vxy, vxz, 1, &gb[row0]);
        batch_barrier(ctr, tgt); tgt += ARRV;
    }

    // ---- EMD: hw = yw + gR;  w as f-phase;  CR = (hw - yw) - w;  P=2^{w+fR} --
    #pragma unroll
    for (int i2 = 0; i2 < 4; ++i2) {
        int k = i2 * WGS + tid;
        ((float*)vhw)[k] = ((const float*)vyw)[k] + aload(&gb[k]);
    }
    float fR[8];
    #pragma unroll
    for (int r = 0; r < 8; ++r) fR[r] = aload(&fb[row0 + r]);
    __syncthreads();

    {
        v2f rx2[8], ry2[8], rz2[8], u02[8];
        const v2f* rp = &rowp[wid * 32];   // ph = 0 (x-rows)
        #pragma unroll
        for (int r = 0; r < 8; ++r) {
            rx2[r] = rp[r*4+0]; ry2[r] = rp[r*4+1];
            rz2[r] = rp[r*4+2]; u02[r] = rp[r*4+3];
        }
        v2f accE; accE.x = 0.f; accE.y = 0.f;
        #pragma unroll 2
        for (int c = 0; c < 16; ++c) {
            int jp = c * 64 + lane;
            v2f X = vyx[jp], Y = vyy[jp], Z = vyz[jp];
            v2f H = vhw[jp], YW = vyw[jp];
            #pragma unroll
            for (int r = 0; r < 8; ++r) {
                v2f w = Z * rz2[r] + (H + u02[r]);
                w = Y * ry2[r] + w;
                w = X * rx2[r] + w;
                v2f cr = (H - YW) - w;
                v2f e;
                e.x = fexp2(w.x + fR[r]) * cr.x;
                e.y = fexp2(w.y + fR[r]) * cr.y;
                accE += e;
            }
        }
        float s = accE.x + accE.y;
        #pragma unroll
        for (int off = 1; off < 64; off <<= 1) s += __shfl_xor(s, off, 64);
        if (lane == 0) wsum[wid] = s;
        __syncthreads();
        if (tid == 0) {
            float t = 0.f;
            #pragma unroll
            for (int i2 = 0; i2 < 8; ++i2) t += wsum[i2];
            atomicAdd(&out[b], t * K_EPS_LN2);
        }
    }
}

// -------------------------------------------------------------- launch ------
extern "C" void kernel_launch(void* const* d_in, const int* in_sizes, int n_in,
                              void* d_out, int out_size, void* d_ws, size_t ws_size,
                              hipStream_t stream)
{
    const float* x = (const float*)d_in[0];
    const float* y = (const float*)d_in[1];
    float* out = (float*)d_out;

    char* ws = (char*)d_ws;
    float4*   px  = (float4*)(ws);
    float4*   py  = (float4*)(ws + (size_t)NB * NPTS * 16);
    float*    f   = (float*)  (ws + (size_t)NB * NPTS * 32);
    float*    g   = (float*)  (ws + (size_t)NB * NPTS * 32 + (size_t)NB * NPTS * 4);
    unsigned* bar = (unsigned*)(ws + (size_t)NB * NPTS * 32 + (size_t)NB * NPTS * 8);

    hipMemsetAsync(d_out, 0, (size_t)out_size * sizeof(float), stream);
    hipMemsetAsync(bar, 0, NB * 64 * sizeof(unsigned), stream);

    prep_kernel<<<(NB * NPTS + 255) / 256, 256, 0, stream>>>(x, y, px, py, g);
    sinkhorn_fused<<<NB * ARRV, WGS, 0, stream>>>(px, py, f, g, bar, out);
}

// Round 11
// 1187.610 us; speedup vs baseline: 1.4547x; 1.0728x over previous
//
#include <hip/hip_runtime.h>

#define NPTS 2048
#define NB   16
#define WGS  1024    // threads per wg (16 waves), 1 wg/CU
#define ARRV 16      // wgs per batch = barrier arrivals

typedef float v2f __attribute__((ext_vector_type(2)));

// eps = 0.01, log-domain Sinkhorn in base-2. Duals stored PRE-SCALED by
// R = 1/(eps*ln2) (log2-units). -log2(2048) = -11 exactly.
constexpr float K_R       = 144.26950408889634f;     // log2(e)/eps
constexpr float K_TWO_R   = 288.53900817779268f;     // 2R
constexpr float K_INV2R   = 0.0034657359027997264f;  // 1/(2R)
constexpr float K_EPS_LN2 = 0.0069314718055994531f;  // 1/R

__device__ __forceinline__ float fexp2(float x) { return __builtin_amdgcn_exp2f(x); }
__device__ __forceinline__ float flog2(float x) { return __builtin_amdgcn_logf(x); }

__device__ __forceinline__ float aload(const float* p) {
    return __hip_atomic_load(p, __ATOMIC_RELAXED, __HIP_MEMORY_SCOPE_AGENT);
}
__device__ __forceinline__ void astore(float* p, float v) {
    __hip_atomic_store(p, v, __ATOMIC_RELAXED, __HIP_MEMORY_SCOPE_AGENT);
}

// ---------------------------------------------------------------- prep ------
// Packed: (p*2R, -|p|^2*R)
__global__ __launch_bounds__(256) void prep_kernel(
    const float* __restrict__ x, const float* __restrict__ y,
    float4* __restrict__ px, float4* __restrict__ py, float* __restrict__ g)
{
    int idx = blockIdx.x * 256 + threadIdx.x;
    if (idx >= NB * NPTS) return;
    float x0 = x[idx*3+0], x1 = x[idx*3+1], x2 = x[idx*3+2];
    float xx = fmaf(x0,x0, fmaf(x1,x1, x2*x2));
    px[idx] = make_float4(x0*K_TWO_R, x1*K_TWO_R, x2*K_TWO_R, -xx*K_R);
    float y0 = y[idx*3+0], y1 = y[idx*3+1], y2 = y[idx*3+2];
    float yy = fmaf(y0,y0, fmaf(y1,y1, y2*y2));
    py[idx] = make_float4(y0*K_TWO_R, y1*K_TWO_R, y2*K_TWO_R, -yy*K_R);
    g[idx] = 0.0f;   // g*R = 0
}

// --------------------------------------------------------- batch barrier ----
// Fence-free monotonic barrier (R9 protocol, verified absmax 0.0).
__device__ __forceinline__ void batch_barrier(unsigned* ctr, unsigned target) {
    __syncthreads();
    if (threadIdx.x == 0) {
        asm volatile("s_waitcnt vmcnt(0)" ::: "memory");
        __hip_atomic_fetch_add(ctr, 1u, __ATOMIC_RELAXED, __HIP_MEMORY_SCOPE_AGENT);
        while (__hip_atomic_load(ctr, __ATOMIC_RELAXED, __HIP_MEMORY_SCOPE_AGENT)
               < target)
            __builtin_amdgcn_s_sleep(1);
        asm volatile("" ::: "memory");
    }
    __syncthreads();
}

// ------------------------------------------------------- persistent core ----
// 256 wgs = 1/CU (LDS ~80 KB). 16 waves/wg, 8 rows/wave. SoA j-pair planes
// in LDS; packed-f32 (v_pk_*) inner loop, 2 visits per pk-chain.
__global__ __launch_bounds__(1024) void sinkhorn_fused(
    const float4* __restrict__ px4, const float4* __restrict__ py4,
    float* __restrict__ f, float* __restrict__ g,
    unsigned* __restrict__ bar, float* __restrict__ out)
{
    __shared__ v2f vyx[1024], vyy[1024], vyz[1024], vyw[1024];  // Y*2R, -|y|^2 R
    __shared__ v2f vxx[1024], vxy[1024], vxz[1024], vxw[1024];  // X*2R, -|x|^2 R
    __shared__ v2f vhw[1024];          // per-phase: wplane + dual (R-units)
    __shared__ v2f rowp[1024];         // pre-broadcast row constants, both phases
    __shared__ float wsum[16];

    const int bid   = blockIdx.x;
    const int b     = bid >> 4;
    const int chunk = bid & 15;
    const int tid   = threadIdx.x;
    const int lane  = tid & 63;
    const int wid   = tid >> 6;           // 0..15
    const int row0  = chunk * 128 + wid * 8;

    const float4* pyb = py4 + b * NPTS;
    const float4* pxb = px4 + b * NPTS;
    float* fb = f + b * NPTS;
    float* gb = g + b * NPTS;
    unsigned* ctr = bar + b * 64;

    // ---- stage SoA planes (2048 elems, 1024 thr) ----
    #pragma unroll
    for (int i2 = 0; i2 < 2; ++i2) {
        int k = i2 * WGS + tid;
        float4 p = pyb[k];
        ((float*)vyx)[k] = p.x; ((float*)vyy)[k] = p.y;
        ((float*)vyz)[k] = p.z; ((float*)vyw)[k] = p.w;
        float4 q2 = pxb[k];
        ((float*)vxx)[k] = q2.x; ((float*)vxy)[k] = q2.y;
        ((float*)vxz)[k] = q2.z; ((float*)vxw)[k] = q2.w;
    }
    // ---- row constants, pre-broadcast into pairs (1 per thread) ----
    {
        int ph  = tid >> 9;                // 0: f-rows (x), 1: g-rows (y)
        int w16 = (tid >> 5) & 15;
        int r   = (tid >> 2) & 7;
        int cp  = tid & 3;
        float4 p = (ph ? pyb : pxb)[chunk * 128 + w16 * 8 + r];
        float v = (cp == 0) ? p.x * K_INV2R :
                  (cp == 1) ? p.y * K_INV2R :
                  (cp == 2) ? p.z * K_INV2R : p.w;
        v2f t; t.x = v; t.y = v;
        rowp[(ph * 16 + w16) * 32 + r * 4 + cp] = t;
    }

    auto run_phase = [&](const v2f* PX, const v2f* PY, const v2f* PZ,
                         int ph, float* dual_out) {
        v2f rx2[8], ry2[8], rz2[8], u02[8];
        const v2f* rp = &rowp[(ph * 16 + wid) * 32];
        #pragma unroll
        for (int r = 0; r < 8; ++r) {
            rx2[r] = rp[r*4+0]; ry2[r] = rp[r*4+1];
            rz2[r] = rp[r*4+2]; u02[r] = rp[r*4+3];
        }
        v2f acc2[8];
        #pragma unroll
        for (int r = 0; r < 8; ++r) { acc2[r].x = 0.f; acc2[r].y = 0.f; }

        #pragma unroll 2
        for (int c = 0; c < 16; ++c) {
            int jp = c * 64 + lane;
            v2f X = PX[jp], Y = PY[jp], Z = PZ[jp], H = vhw[jp];
            #pragma unroll
            for (int r = 0; r < 8; ++r) {
                v2f w = Z * rz2[r] + (H + u02[r]);
                w = Y * ry2[r] + w;
                w = X * rx2[r] + w;
                v2f e; e.x = fexp2(w.x); e.y = fexp2(w.y);
                acc2[r] += e;
            }
        }

        float sv[8];
        #pragma unroll
        for (int r = 0; r < 8; ++r) {
            float s = acc2[r].x + acc2[r].y;
            #pragma unroll
            for (int off = 1; off < 64; off <<= 1)
                s += __shfl_xor(s, off, 64);
            sv[r] = s;
        }
        if (lane < 8) {
            float s = sv[0];
            #pragma unroll
            for (int r = 1; r < 8; ++r) s = (lane == r) ? sv[r] : s;
            astore(&dual_out[lane], -11.0f - flog2(s));
        }
    };

    unsigned tgt = ARRV;
    for (int it = 0; it < 50; ++it) {
        // ---- f-update: hw = yw + gR ----
        #pragma unroll
        for (int i2 = 0; i2 < 2; ++i2) {
            int k = i2 * WGS + tid;
            ((float*)vhw)[k] = ((const float*)vyw)[k] + aload(&gb[k]);
        }
        __syncthreads();
        run_phase(vyx, vyy, vyz, 0, &fb[row0]);
        batch_barrier(ctr, tgt); tgt += ARRV;

        // ---- g-update: hw = xw + fR ----
        #pragma unroll
        for (int i2 = 0; i2 < 2; ++i2) {
            int k = i2 * WGS + tid;
            ((float*)vhw)[k] = ((const float*)vxw)[k] + aload(&fb[k]);
        }
        __syncthreads();
        run_phase(vxx, vxy, vxz, 1, &gb[row0]);
        batch_barrier(ctr, tgt); tgt += ARRV;
    }

    // ---- EMD: hw = yw + gR;  w as f-phase;  CR = (hw - yw) - w;  P=2^{w+fR} --
    #pragma unroll
    for (int i2 = 0; i2 < 2; ++i2) {
        int k = i2 * WGS + tid;
        ((float*)vhw)[k] = ((const float*)vyw)[k] + aload(&gb[k]);
    }
    float fR[8];
    #pragma unroll
    for (int r = 0; r < 8; ++r) fR[r] = aload(&fb[row0 + r]);
    __syncthreads();

    {
        v2f rx2[8], ry2[8], rz2[8], u02[8];
        const v2f* rp = &rowp[wid * 32];   // ph = 0 (x-rows)
        #pragma unroll
        for (int r = 0; r < 8; ++r) {
            rx2[r] = rp[r*4+0]; ry2[r] = rp[r*4+1];
            rz2[r] = rp[r*4+2]; u02[r] = rp[r*4+3];
        }
        v2f accE; accE.x = 0.f; accE.y = 0.f;
        #pragma unroll 2
        for (int c = 0; c < 16; ++c) {
            int jp = c * 64 + lane;
            v2f X = vyx[jp], Y = vyy[jp], Z = vyz[jp];
            v2f H = vhw[jp], YW = vyw[jp];
            #pragma unroll
            for (int r = 0; r < 8; ++r) {
                v2f w = Z * rz2[r] + (H + u02[r]);
                w = Y * ry2[r] + w;
                w = X * rx2[r] + w;
                v2f cr = (H - YW) - w;
                v2f e;
                e.x = fexp2(w.x + fR[r]) * cr.x;
                e.y = fexp2(w.y + fR[r]) * cr.y;
                accE += e;
            }
        }
        float s = accE.x + accE.y;
        #pragma unroll
        for (int off = 1; off < 64; off <<= 1) s += __shfl_xor(s, off, 64);
        if (lane == 0) wsum[wid] = s;
        __syncthreads();
        if (tid == 0) {
            float t = 0.f;
            #pragma unroll
            for (int i2 = 0; i2 < 16; ++i2) t += wsum[i2];
            atomicAdd(&out[b], t * K_EPS_LN2);
        }
    }
}

// -------------------------------------------------------------- launch ------
extern "C" void kernel_launch(void* const* d_in, const int* in_sizes, int n_in,
                              void* d_out, int out_size, void* d_ws, size_t ws_size,
                              hipStream_t stream)
{
    const float* x = (const float*)d_in[0];
    const float* y = (const float*)d_in[1];
    float* out = (float*)d_out;

    char* ws = (char*)d_ws;
    float4*   px  = (float4*)(ws);
    float4*   py  = (float4*)(ws + (size_t)NB * NPTS * 16);
    float*    f   = (float*)  (ws + (size_t)NB * NPTS * 32);
    float*    g   = (float*)  (ws + (size_t)NB * NPTS * 32 + (size_t)NB * NPTS * 4);
    unsigned* bar = (unsigned*)(ws + (size_t)NB * NPTS * 32 + (size_t)NB * NPTS * 8);

    hipMemsetAsync(d_out, 0, (size_t)out_size * sizeof(float), stream);
    hipMemsetAsync(bar, 0, NB * 64 * sizeof(unsigned), stream);

    prep_kernel<<<(NB * NPTS + 255) / 256, 256, 0, stream>>>(x, y, px, py, g);
    sinkhorn_fused<<<NB * ARRV, WGS, 0, stream>>>(px, py, f, g, bar, out);
}

// Round 12
// 1165.828 us; speedup vs baseline: 1.4819x; 1.0187x over previous
//
#include <hip/hip_runtime.h>

#define NPTS 2048
#define NB   16
#define WGS  1024    // threads per wg (16 waves), 1 wg/CU
#define ARRV 16      // wgs per batch = barrier arrivals

typedef float v2f __attribute__((ext_vector_type(2)));

// eps = 0.01, log-domain Sinkhorn in base-2. Duals stored PRE-SCALED by
// R = 1/(eps*ln2) (log2-units) and PRE-SHIFTED by the owner's plane const:
//   fs_i = fR_i + xw_i,   gs_j = gR_j + yw_j   (xw = -|x|^2 R, yw = -|y|^2 R)
// -log2(2048) = -11 exactly.
constexpr float K_R       = 144.26950408889634f;     // log2(e)/eps
constexpr float K_TWO_R   = 288.53900817779268f;     // 2R
constexpr float K_INV2R   = 0.0034657359027997264f;  // 1/(2R)
constexpr float K_EPS_LN2 = 0.0069314718055994531f;  // 1/R

__device__ __forceinline__ float fexp2(float x) { return __builtin_amdgcn_exp2f(x); }
__device__ __forceinline__ float flog2(float x) { return __builtin_amdgcn_logf(x); }

__device__ __forceinline__ float aload(const float* p) {
    return __hip_atomic_load(p, __ATOMIC_RELAXED, __HIP_MEMORY_SCOPE_AGENT);
}
__device__ __forceinline__ v2f aload2(const float* p) {
    unsigned long long v = __hip_atomic_load((const unsigned long long*)p,
                           __ATOMIC_RELAXED, __HIP_MEMORY_SCOPE_AGENT);
    union { unsigned long long u; v2f f; } c; c.u = v; return c.f;
}
__device__ __forceinline__ void astore(float* p, float v) {
    __hip_atomic_store(p, v, __ATOMIC_RELAXED, __HIP_MEMORY_SCOPE_AGENT);
}

// ---------------------------------------------------------------- prep ------
// Packed: (p*2R, -|p|^2*R); g initialized PRE-SHIFTED: gs = 0 + yw = yw.
__global__ __launch_bounds__(256) void prep_kernel(
    const float* __restrict__ x, const float* __restrict__ y,
    float4* __restrict__ px, float4* __restrict__ py, float* __restrict__ g)
{
    int idx = blockIdx.x * 256 + threadIdx.x;
    if (idx >= NB * NPTS) return;
    float x0 = x[idx*3+0], x1 = x[idx*3+1], x2 = x[idx*3+2];
    float xx = fmaf(x0,x0, fmaf(x1,x1, x2*x2));
    px[idx] = make_float4(x0*K_TWO_R, x1*K_TWO_R, x2*K_TWO_R, -xx*K_R);
    float y0 = y[idx*3+0], y1 = y[idx*3+1], y2 = y[idx*3+2];
    float yy = fmaf(y0,y0, fmaf(y1,y1, y2*y2));
    py[idx] = make_float4(y0*K_TWO_R, y1*K_TWO_R, y2*K_TWO_R, -yy*K_R);
    g[idx] = -yy*K_R;   // gs = yw
}

// --------------------------------------------------------- batch barrier ----
// Fence-free monotonic barrier (R9 protocol, verified absmax 0.0).
__device__ __forceinline__ void batch_barrier(unsigned* ctr, unsigned target) {
    __syncthreads();
    if (threadIdx.x == 0) {
        asm volatile("s_waitcnt vmcnt(0)" ::: "memory");
        __hip_atomic_fetch_add(ctr, 1u, __ATOMIC_RELAXED, __HIP_MEMORY_SCOPE_AGENT);
        while (__hip_atomic_load(ctr, __ATOMIC_RELAXED, __HIP_MEMORY_SCOPE_AGENT)
               < target)
            __builtin_amdgcn_s_sleep(1);
        asm volatile("" ::: "memory");
    }
    __syncthreads();
}

// ------------------------------------------------------- persistent core ----
// 256 wgs = 1/CU (LDS ~74 KB). 16 waves/wg, 8 rows/wave. SoA j-pair planes
// in LDS; packed-f32 inner loop. Staging = pure copy (duals pre-shifted).
__global__ __launch_bounds__(1024) void sinkhorn_fused(
    const float4* __restrict__ px4, const float4* __restrict__ py4,
    float* __restrict__ f, float* __restrict__ g,
    unsigned* __restrict__ bar, float* __restrict__ out)
{
    __shared__ v2f vyx[1024], vyy[1024], vyz[1024], vyw[1024];  // Y*2R; yw (EMD)
    __shared__ v2f vxx[1024], vxy[1024], vxz[1024];             // X*2R
    __shared__ v2f vhw[1024];          // per-phase: staged pre-shifted duals
    __shared__ v2f rowp[1024];         // pre-broadcast row constants
    __shared__ float wsum[16];

    const int bid   = blockIdx.x;
    const int b     = bid >> 4;
    const int chunk = bid & 15;
    const int tid   = threadIdx.x;
    const int lane  = tid & 63;
    const int wid   = tid >> 6;           // 0..15
    const int row0  = chunk * 128 + wid * 8;

    const float4* pyb = py4 + b * NPTS;
    const float4* pxb = px4 + b * NPTS;
    float* fb = f + b * NPTS;
    float* gb = g + b * NPTS;
    unsigned* ctr = bar + b * 64;

    // ---- stage SoA planes (2048 elems, 1024 thr) ----
    #pragma unroll
    for (int i2 = 0; i2 < 2; ++i2) {
        int k = i2 * WGS + tid;
        float4 p = pyb[k];
        ((float*)vyx)[k] = p.x; ((float*)vyy)[k] = p.y;
        ((float*)vyz)[k] = p.z; ((float*)vyw)[k] = p.w;
        float4 q2 = pxb[k];
        ((float*)vxx)[k] = q2.x; ((float*)vxy)[k] = q2.y;
        ((float*)vxz)[k] = q2.z;
    }
    // ---- row constants, pre-broadcast into pairs (1 per thread) ----
    {
        int ph  = tid >> 9;                // 0: f-rows (x), 1: g-rows (y)
        int w16 = (tid >> 5) & 15;
        int r   = (tid >> 2) & 7;
        int cp  = tid & 3;
        float4 p = (ph ? pyb : pxb)[chunk * 128 + w16 * 8 + r];
        float v = (cp == 0) ? p.x * K_INV2R :
                  (cp == 1) ? p.y * K_INV2R :
                  (cp == 2) ? p.z * K_INV2R : p.w;
        v2f t; t.x = v; t.y = v;
        rowp[(ph * 16 + w16) * 32 + r * 4 + cp] = t;
    }

    // dual_out gets PRE-SHIFTED value: -11 - log2(s) + u0_row
    auto run_phase = [&](const v2f* PX, const v2f* PY, const v2f* PZ,
                         int ph, float* dual_out) {
        v2f rx2[8], ry2[8], rz2[8], u02[8];
        const v2f* rp = &rowp[(ph * 16 + wid) * 32];
        #pragma unroll
        for (int r = 0; r < 8; ++r) {
            rx2[r] = rp[r*4+0]; ry2[r] = rp[r*4+1];
            rz2[r] = rp[r*4+2]; u02[r] = rp[r*4+3];
        }
        v2f acc2[8];
        #pragma unroll
        for (int r = 0; r < 8; ++r) { acc2[r].x = 0.f; acc2[r].y = 0.f; }

        #pragma unroll 2
        for (int c = 0; c < 16; ++c) {
            int jp = c * 64 + lane;
            v2f X = PX[jp], Y = PY[jp], Z = PZ[jp], H = vhw[jp];
            #pragma unroll
            for (int r = 0; r < 8; ++r) {
                v2f w = Z * rz2[r] + (H + u02[r]);
                w = Y * ry2[r] + w;
                w = X * rx2[r] + w;
                v2f e; e.x = fexp2(w.x); e.y = fexp2(w.y);
                acc2[r] += e;
            }
        }

        float sv[8];
        #pragma unroll
        for (int r = 0; r < 8; ++r) {
            float s = acc2[r].x + acc2[r].y;
            #pragma unroll
            for (int off = 1; off < 64; off <<= 1)
                s += __shfl_xor(s, off, 64);
            sv[r] = s;
        }
        if (lane < 8) {
            float s = sv[0];
            #pragma unroll
            for (int r = 1; r < 8; ++r) s = (lane == r) ? sv[r] : s;
            float u0s = ((const float*)&rp[lane * 4 + 3])[0];  // LDS re-read
            astore(&dual_out[lane], -11.0f - flog2(s) + u0s);
        }
    };

    unsigned tgt = ARRV;
    for (int it = 0; it < 50; ++it) {
        // ---- f-update: stage gs (pure copy, 1 x 8B per thread) ----
        vhw[tid] = aload2(&gb[2 * tid]);
        __syncthreads();
        run_phase(vyx, vyy, vyz, 0, &fb[row0]);
        batch_barrier(ctr, tgt); tgt += ARRV;

        // ---- g-update: stage fs ----
        vhw[tid] = aload2(&fb[2 * tid]);
        __syncthreads();
        run_phase(vxx, vxy, vxz, 1, &gb[row0]);
        batch_barrier(ctr, tgt); tgt += ARRV;
    }

    // ---- EMD: H = gs;  w = 2Rx.y + gs + xw = gR - CR;  CR = (H-YW) - w;
    //      P = 2^(w + fR),  fR = fs - xw ----
    vhw[tid] = aload2(&gb[2 * tid]);
    const v2f* rpf = &rowp[wid * 32];   // ph=0 x-rows
    float fR[8];
    #pragma unroll
    for (int r = 0; r < 8; ++r) {
        float xw = ((const float*)&rpf[r * 4 + 3])[0];
        fR[r] = aload(&fb[row0 + r]) - xw;
    }
    __syncthreads();

    {
        v2f rx2[8], ry2[8], rz2[8], u02[8];
        #pragma unroll
        for (int r = 0; r < 8; ++r) {
            rx2[r] = rpf[r*4+0]; ry2[r] = rpf[r*4+1];
            rz2[r] = rpf[r*4+2]; u02[r] = rpf[r*4+3];
        }
        v2f accE; accE.x = 0.f; accE.y = 0.f;
        #pragma unroll 2
        for (int c = 0; c < 16; ++c) {
            int jp = c * 64 + lane;
            v2f X = vyx[jp], Y = vyy[jp], Z = vyz[jp];
            v2f H = vhw[jp], YW = vyw[jp];
            #pragma unroll
            for (int r = 0; r < 8; ++r) {
                v2f w = Z * rz2[r] + (H + u02[r]);
                w = Y * ry2[r] + w;
                w = X * rx2[r] + w;
                v2f cr = (H - YW) - w;
                v2f e;
                e.x = fexp2(w.x + fR[r]) * cr.x;
                e.y = fexp2(w.y + fR[r]) * cr.y;
                accE += e;
            }
        }
        float s = accE.x + accE.y;
        #pragma unroll
        for (int off = 1; off < 64; off <<= 1) s += __shfl_xor(s, off, 64);
        if (lane == 0) wsum[wid] = s;
        __syncthreads();
        if (tid == 0) {
            float t = 0.f;
            #pragma unroll
            for (int i2 = 0; i2 < 16; ++i2) t += wsum[i2];
            atomicAdd(&out[b], t * K_EPS_LN2);
        }
    }
}

// -------------------------------------------------------------- launch ------
extern "C" void kernel_launch(void* const* d_in, const int* in_sizes, int n_in,
                              void* d_out, int out_size, void* d_ws, size_t ws_size,
                              hipStream_t stream)
{
    const float* x = (const float*)d_in[0];
    const float* y = (const float*)d_in[1];
    float* out = (float*)d_out;

    char* ws = (char*)d_ws;
    float4*   px  = (float4*)(ws);
    float4*   py  = (float4*)(ws + (size_t)NB * NPTS * 16);
    float*    f   = (float*)  (ws + (size_t)NB * NPTS * 32);
    float*    g   = (float*)  (ws + (size_t)NB * NPTS * 32 + (size_t)NB * NPTS * 4);
    unsigned* bar = (unsigned*)(ws + (size_t)NB * NPTS * 32 + (size_t)NB * NPTS * 8);

    hipMemsetAsync(d_out, 0, (size_t)out_size * sizeof(float), stream);
    hipMemsetAsync(bar, 0, NB * 64 * sizeof(unsigned), stream);

    prep_kernel<<<(NB * NPTS + 255) / 256, 256, 0, stream>>>(x, y, px, py, g);
    sinkhorn_fused<<<NB * ARRV, WGS, 0, stream>>>(px, py, f, g, bar, out);
}